// Round 4
// baseline (1594.401 us; speedup 1.0000x reference)
//
#include <hip/hip_runtime.h>
#include <hip/hip_bf16.h>
#include <math.h>

// CVQNN classifier, N=64 modes, OUT=10, HBAR=2.
// Kernel 1 (1 block, 192 thr): build S (128x128 symplectic, 2 layers) and d.
//   Thread c holds column c of S in registers (ops are column-local).
//   Thread 128 carries the displacement vector d through the same ops.
//   Emits to ws: W[k][rr] = 2*S[rows[rr],k] (k<64, 1280 fl),
//                bias[rr] = d[rows[rr]] (20 fl), cterm[w] (10 fl).
// Kernel 2: W/bias/cterm in LDS (uniform-address broadcast reads, ~free).
//   One row per thread. Row read as TWO bursts of 8 back-to-back
//   global_load_dwordx4 (each burst = exactly one 128B cache line; rows are
//   256B-aligned so bursts never straddle lines). Round-3 lesson: 16-B
//   granular dist-1 loads touched each line 8x spread over the loop ->
//   L2 thrash (FETCH 400MB vs 256MB ideal) + 1-deep MLP (2.7 TB/s).
//   Bursts make each line read once by one thread (compulsory traffic only)
//   and give 8-deep MLP. Reg budget: xr[8]=32 + acc[20] + addr ~8 = ~60,
//   fits the 64-reg cap of launch_bounds(256,4) (round-2 lesson: (256,4)
//   => 64-reg cap; spill shows up as GB-scale FETCH/WRITE -> abort signal).
//   #pragma unroll 1 on the half-loop stops cross-half load hoisting.

#define TWO_N 128
#define OUT_N 10
#define LSTRIDE 758
// per-layer trig table layout (stride 758):
// [0,63) ct1 [63,126) st1 [126,189) cp1 [189,252) sp1
// [252,315) rot_c [315,378) rot_s [378,442) exp(-sq) [442,506) exp(+sq)
// [506,758) int2 trig (same sublayout as int1)

template<int S>
__device__ __forceinline__ void bs_apply(float (&col)[TWO_N], const float* t){
  #pragma unroll
  for (int i = S; i < 63; i += 2){
    float ct = t[i], st = t[63+i], cp = t[126+i], sp = t[189+i];
    float cs = cp*st, ss = sp*st;
    float a = col[i], b = col[i+1], e = col[64+i], f = col[65+i];
    col[i]    = ct*a - cs*b - ss*f;
    col[i+1]  = cs*a + ct*b - ss*e;
    col[64+i] = ss*b + ct*e - cs*f;
    col[65+i] = ss*a + cs*e + ct*f;
  }
}

__device__ __forceinline__ void rot_squeeze(float (&col)[TWO_N], const float* t){
  #pragma unroll
  for (int m = 0; m < 64; ++m){
    float cm = (m < 63) ? t[252+m] : 1.0f;
    float sm = (m < 63) ? t[315+m] : 0.0f;
    float em = t[378+m], ep = t[442+m];
    float u = col[m], v = col[64+m];
    col[m]    = em * (cm*u - sm*v);
    col[64+m] = ep * (sm*u + cm*v);
  }
}

__global__ __launch_bounds__(192, 1)
void cvqnn_setup(const float* __restrict__ i1_0, const float* __restrict__ sq_0,
                 const float* __restrict__ i2_0, const float* __restrict__ dp_0,
                 const float* __restrict__ i1_1, const float* __restrict__ sq_1,
                 const float* __restrict__ i2_1, const float* __restrict__ dp_1,
                 float* __restrict__ ws)
{
  __shared__ float trig[2*LSTRIDE];
  __shared__ float red[128*OUT_N];
  const int tid = threadIdx.x;

  // ---- parallel transcendental precompute ----
  for (int idx = tid; idx < 2*LSTRIDE; idx += 192){
    int L = idx / LSTRIDE, q = idx - L*LSTRIDE;
    const float* i1 = L ? i1_1 : i1_0;
    const float* i2 = L ? i2_1 : i2_0;
    const float* sq = L ? sq_1 : sq_0;
    float v;
    if (q < 252){
      int kind = q / 63, i = q - kind*63;
      float ang = (kind & 2) ? i1[3*i+1] : i1[3*i];
      v = (kind & 1) ? sinf(ang) : cosf(ang);
    } else if (q < 378){
      int kind = (q-252)/63, m = (q-252) - kind*63;
      float ang = i1[3*m+2];
      v = kind ? sinf(ang) : cosf(ang);
    } else if (q < 506){
      int kind = (q-378)/64, m = (q-378) - kind*64;
      v = expf(kind ? sq[m] : -sq[m]);
    } else {
      int qq = q - 506;
      int kind = qq / 63, i = qq - kind*63;
      float ang = (kind & 2) ? i2[3*i+1] : i2[3*i];
      v = (kind & 1) ? sinf(ang) : cosf(ang);
    }
    trig[idx] = v;
  }
  __syncthreads();

  // ---- column-local transform (no syncs needed: ops mix rows, not cols) ----
  float col[TWO_N];
  const int c = tid;
  if (c < 129){
    #pragma unroll
    for (int r = 0; r < TWO_N; ++r) col[r] = (r == c) ? 1.0f : 0.0f; // c==128 -> zeros (d)

    #pragma unroll
    for (int L = 0; L < 2; ++L){
      const float* tl = trig + L*LSTRIDE;
      bs_apply<0>(col, tl);
      bs_apply<1>(col, tl);
      rot_squeeze(col, tl);
      bs_apply<0>(col, tl + 506);
      bs_apply<1>(col, tl + 506);
      if (c == 128){
        const float* dp = L ? dp_1 : dp_0;
        #pragma unroll
        for (int m = 0; m < 64; ++m) col[m] += 2.0f * dp[m];
      }
    }

    // rows of interest: rr<10 -> row rr ; rr>=10 -> row 64+(rr-10) = 54+rr
    if (c < 64){
      #pragma unroll
      for (int rr = 0; rr < 20; ++rr){
        int row = (rr < 10) ? rr : (54 + rr);
        ws[c*20 + rr] = 2.0f * col[row];   // W[k=c][rr], factor 2 folded in
      }
    }
    if (c < 128){
      #pragma unroll
      for (int w = 0; w < OUT_N; ++w)
        red[c*OUT_N + w] = col[w]*col[w] + col[64+w]*col[64+w];
    }
    if (c == 128){
      #pragma unroll
      for (int rr = 0; rr < 20; ++rr){
        int row = (rr < 10) ? rr : (54 + rr);
        ws[1280 + rr] = col[row];          // bias = d[rows]
      }
    }
  }
  __syncthreads();
  if (tid < OUT_N){
    float s = 0.0f;
    for (int k = 0; k < 128; ++k) s += red[k*OUT_N + tid];
    ws[1300 + tid] = s;                    // cov_term[w]
  }
}

__global__ __launch_bounds__(256, 4)
void cvqnn_main(const float* __restrict__ x, const float* __restrict__ ws,
                float* __restrict__ out, int B)
{
  // shs: [0,1280) W (layout k*20+rr), [1280,1300) bias, [1300,1310) cterm
  __shared__ __align__(16) float shs[1310];
  const int tid = threadIdx.x;
  #pragma unroll
  for (int i = 0; i < 6; ++i){
    int idx = i*256 + tid;
    if (idx < 1310) shs[idx] = ws[idx];
  }
  __syncthreads();

  const int b = blockIdx.x * 256 + tid;
  const bool v = b < B;
  const int rb = v ? b : 0;               // clamp OOB rows: load row 0, never store

  const float4* x4 = reinterpret_cast<const float4*>(x) + ((size_t)rb << 4);

  float acc[20];
  #pragma unroll
  for (int r = 0; r < 20; ++r) acc[r] = shs[1280 + r];   // bias (broadcast)

  #pragma unroll 1   // keep halves separate: live set = xr[8]+acc[20] ~ 60 regs
  for (int half = 0; half < 2; ++half){
    // one full 128B cache line, 8 back-to-back dwordx4 (1 base + imm offsets)
    float4 xr[8];
    #pragma unroll
    for (int i = 0; i < 8; ++i) xr[i] = x4[(half << 3) + i];

    const float* wh = shs + half*640;
    #pragma unroll
    for (int k4 = 0; k4 < 8; ++k4){
      float4 cx = xr[k4];                 // compile-time index -> stays in regs
      const float* wb = wh + k4*80;       // uniform LDS address -> broadcast
      #pragma unroll
      for (int q = 0; q < 4; ++q){
        float xs = (q == 0) ? cx.x : (q == 1) ? cx.y : (q == 2) ? cx.z : cx.w;
        const float4* wv = reinterpret_cast<const float4*>(wb + q*20);
        #pragma unroll
        for (int m = 0; m < 5; ++m){
          float4 w = wv[m];
          acc[4*m+0] = fmaf(xs, w.x, acc[4*m+0]);
          acc[4*m+1] = fmaf(xs, w.y, acc[4*m+1]);
          acc[4*m+2] = fmaf(xs, w.z, acc[4*m+2]);
          acc[4*m+3] = fmaf(xs, w.w, acc[4*m+3]);
        }
      }
    }
  }

  if (v){
    float2* o = reinterpret_cast<float2*>(out + (size_t)b * 10); // 40B row, 8B aligned
    #pragma unroll
    for (int w = 0; w < OUT_N; w += 2){
      float mx0 = acc[w],   mp0 = acc[10+w];
      float nm0 = (shs[1300+w] + mx0*mx0 + mp0*mp0) * 0.25f - 0.5f;
      float r0  = log1pf(fmaxf(nm0, 0.0f));
      float mx1 = acc[w+1], mp1 = acc[11+w];
      float nm1 = (shs[1301+w] + mx1*mx1 + mp1*mp1) * 0.25f - 0.5f;
      float r1  = log1pf(fmaxf(nm1, 0.0f));
      o[w >> 1] = make_float2(r0, r1);
    }
  }
}

extern "C" void kernel_launch(void* const* d_in, const int* in_sizes, int n_in,
                              void* d_out, int out_size, void* d_ws, size_t ws_size,
                              hipStream_t stream)
{
  const float* x    = (const float*)d_in[0];
  const float* i1_0 = (const float*)d_in[1];
  const float* sq_0 = (const float*)d_in[2];
  const float* i2_0 = (const float*)d_in[3];
  const float* dp_0 = (const float*)d_in[4];
  const float* i1_1 = (const float*)d_in[5];
  const float* sq_1 = (const float*)d_in[6];
  const float* i2_1 = (const float*)d_in[7];
  const float* dp_1 = (const float*)d_in[8];
  float* ws = (float*)d_ws;

  int B = in_sizes[0] / 64;

  cvqnn_setup<<<1, 192, 0, stream>>>(i1_0, sq_0, i2_0, dp_0,
                                     i1_1, sq_1, i2_1, dp_1, ws);

  int grid = (B + 255) / 256;   // 256 rows per block, exact, balanced
  cvqnn_main<<<grid, 256, 0, stream>>>(x, ws, (float*)d_out, B);
}

// Round 5
// 431.497 us; speedup vs baseline: 3.6950x; 3.6950x over previous
//
#include <hip/hip_runtime.h>
#include <hip/hip_bf16.h>
#include <math.h>

// CVQNN classifier, N=64 modes, OUT=10, HBAR=2.
// Kernel 1 (1 block, 192 thr): build S (128x128 symplectic, 2 layers) and d.
//   Thread c holds column c of S in registers (ops are column-local).
//   Thread 128 carries the displacement vector d through the same ops.
//   Emits to ws: W[k][rr] = 2*S[rows[rr],k] (k<64, 1280 fl),
//                bias[rr] = d[rows[rr]] (20 fl), cterm[w] (10 fl).
// Kernel 2: W/bias/cterm in LDS (uniform-address broadcast reads, ~free).
//   One row per thread. Row read as TWO bursts of 8 back-to-back
//   global_load_dwordx4 (burst = exactly one 128B line; rows 256B-aligned).
//   Round-3 lesson: 16B granular loads touch each line 8x spread over the
//   loop -> L2 thrash (FETCH 1.56x ideal) + 1-deep MLP (2.7 TB/s).
//   Round-4 lesson: burst structure needs ~75+ live regs; under the 64-reg
//   cap of launch_bounds(256,4) it SPILLED (FETCH 2GB, WRITE 3.7GB, 1364us).
//   Fix: launch_bounds(256,2) -> 128-reg cap (one occupancy step looser,
//   16 waves/CU). 16 waves/CU x 8 outstanding loads = ample MLP; spill
//   signature (VGPR pinned at cap + GB-scale FETCH/WRITE) = abort signal.

#define TWO_N 128
#define OUT_N 10
#define LSTRIDE 758
// per-layer trig table layout (stride 758):
// [0,63) ct1 [63,126) st1 [126,189) cp1 [189,252) sp1
// [252,315) rot_c [315,378) rot_s [378,442) exp(-sq) [442,506) exp(+sq)
// [506,758) int2 trig (same sublayout as int1)

template<int S>
__device__ __forceinline__ void bs_apply(float (&col)[TWO_N], const float* t){
  #pragma unroll
  for (int i = S; i < 63; i += 2){
    float ct = t[i], st = t[63+i], cp = t[126+i], sp = t[189+i];
    float cs = cp*st, ss = sp*st;
    float a = col[i], b = col[i+1], e = col[64+i], f = col[65+i];
    col[i]    = ct*a - cs*b - ss*f;
    col[i+1]  = cs*a + ct*b - ss*e;
    col[64+i] = ss*b + ct*e - cs*f;
    col[65+i] = ss*a + cs*e + ct*f;
  }
}

__device__ __forceinline__ void rot_squeeze(float (&col)[TWO_N], const float* t){
  #pragma unroll
  for (int m = 0; m < 64; ++m){
    float cm = (m < 63) ? t[252+m] : 1.0f;
    float sm = (m < 63) ? t[315+m] : 0.0f;
    float em = t[378+m], ep = t[442+m];
    float u = col[m], v = col[64+m];
    col[m]    = em * (cm*u - sm*v);
    col[64+m] = ep * (sm*u + cm*v);
  }
}

__global__ __launch_bounds__(192, 1)
void cvqnn_setup(const float* __restrict__ i1_0, const float* __restrict__ sq_0,
                 const float* __restrict__ i2_0, const float* __restrict__ dp_0,
                 const float* __restrict__ i1_1, const float* __restrict__ sq_1,
                 const float* __restrict__ i2_1, const float* __restrict__ dp_1,
                 float* __restrict__ ws)
{
  __shared__ float trig[2*LSTRIDE];
  __shared__ float red[128*OUT_N];
  const int tid = threadIdx.x;

  // ---- parallel transcendental precompute ----
  for (int idx = tid; idx < 2*LSTRIDE; idx += 192){
    int L = idx / LSTRIDE, q = idx - L*LSTRIDE;
    const float* i1 = L ? i1_1 : i1_0;
    const float* i2 = L ? i2_1 : i2_0;
    const float* sq = L ? sq_1 : sq_0;
    float v;
    if (q < 252){
      int kind = q / 63, i = q - kind*63;
      float ang = (kind & 2) ? i1[3*i+1] : i1[3*i];
      v = (kind & 1) ? sinf(ang) : cosf(ang);
    } else if (q < 378){
      int kind = (q-252)/63, m = (q-252) - kind*63;
      float ang = i1[3*m+2];
      v = kind ? sinf(ang) : cosf(ang);
    } else if (q < 506){
      int kind = (q-378)/64, m = (q-378) - kind*64;
      v = expf(kind ? sq[m] : -sq[m]);
    } else {
      int qq = q - 506;
      int kind = qq / 63, i = qq - kind*63;
      float ang = (kind & 2) ? i2[3*i+1] : i2[3*i];
      v = (kind & 1) ? sinf(ang) : cosf(ang);
    }
    trig[idx] = v;
  }
  __syncthreads();

  // ---- column-local transform (no syncs needed: ops mix rows, not cols) ----
  float col[TWO_N];
  const int c = tid;
  if (c < 129){
    #pragma unroll
    for (int r = 0; r < TWO_N; ++r) col[r] = (r == c) ? 1.0f : 0.0f; // c==128 -> zeros (d)

    #pragma unroll
    for (int L = 0; L < 2; ++L){
      const float* tl = trig + L*LSTRIDE;
      bs_apply<0>(col, tl);
      bs_apply<1>(col, tl);
      rot_squeeze(col, tl);
      bs_apply<0>(col, tl + 506);
      bs_apply<1>(col, tl + 506);
      if (c == 128){
        const float* dp = L ? dp_1 : dp_0;
        #pragma unroll
        for (int m = 0; m < 64; ++m) col[m] += 2.0f * dp[m];
      }
    }

    // rows of interest: rr<10 -> row rr ; rr>=10 -> row 64+(rr-10) = 54+rr
    if (c < 64){
      #pragma unroll
      for (int rr = 0; rr < 20; ++rr){
        int row = (rr < 10) ? rr : (54 + rr);
        ws[c*20 + rr] = 2.0f * col[row];   // W[k=c][rr], factor 2 folded in
      }
    }
    if (c < 128){
      #pragma unroll
      for (int w = 0; w < OUT_N; ++w)
        red[c*OUT_N + w] = col[w]*col[w] + col[64+w]*col[64+w];
    }
    if (c == 128){
      #pragma unroll
      for (int rr = 0; rr < 20; ++rr){
        int row = (rr < 10) ? rr : (54 + rr);
        ws[1280 + rr] = col[row];          // bias = d[rows]
      }
    }
  }
  __syncthreads();
  if (tid < OUT_N){
    float s = 0.0f;
    for (int k = 0; k < 128; ++k) s += red[k*OUT_N + tid];
    ws[1300 + tid] = s;                    // cov_term[w]
  }
}

__global__ __launch_bounds__(256, 2)
void cvqnn_main(const float* __restrict__ x, const float* __restrict__ ws,
                float* __restrict__ out, int B)
{
  // shs: [0,1280) W (layout k*20+rr), [1280,1300) bias, [1300,1310) cterm
  __shared__ __align__(16) float shs[1310];
  const int tid = threadIdx.x;
  #pragma unroll
  for (int i = 0; i < 6; ++i){
    int idx = i*256 + tid;
    if (idx < 1310) shs[idx] = ws[idx];
  }
  __syncthreads();

  const int b = blockIdx.x * 256 + tid;
  const bool v = b < B;
  const int rb = v ? b : 0;               // clamp OOB rows: load row 0, never store

  const float4* x4 = reinterpret_cast<const float4*>(x) + ((size_t)rb << 4);

  float acc[20];
  #pragma unroll
  for (int r = 0; r < 20; ++r) acc[r] = shs[1280 + r];   // bias (broadcast)

  #pragma unroll 1   // keep halves separate: live set = xr[8]+acc[20]+addr ~75
  for (int half = 0; half < 2; ++half){
    // one full 128B cache line, 8 back-to-back dwordx4 (1 base + imm offsets)
    float4 xr[8];
    #pragma unroll
    for (int i = 0; i < 8; ++i) xr[i] = x4[(half << 3) + i];

    const float* wh = shs + half*640;
    #pragma unroll
    for (int k4 = 0; k4 < 8; ++k4){
      float4 cx = xr[k4];                 // compile-time index -> stays in regs
      const float* wb = wh + k4*80;       // uniform LDS address -> broadcast
      #pragma unroll
      for (int q = 0; q < 4; ++q){
        float xs = (q == 0) ? cx.x : (q == 1) ? cx.y : (q == 2) ? cx.z : cx.w;
        const float4* wv = reinterpret_cast<const float4*>(wb + q*20);
        #pragma unroll
        for (int m = 0; m < 5; ++m){
          float4 w = wv[m];
          acc[4*m+0] = fmaf(xs, w.x, acc[4*m+0]);
          acc[4*m+1] = fmaf(xs, w.y, acc[4*m+1]);
          acc[4*m+2] = fmaf(xs, w.z, acc[4*m+2]);
          acc[4*m+3] = fmaf(xs, w.w, acc[4*m+3]);
        }
      }
    }
  }

  if (v){
    float2* o = reinterpret_cast<float2*>(out + (size_t)b * 10); // 40B row, 8B aligned
    #pragma unroll
    for (int w = 0; w < OUT_N; w += 2){
      float mx0 = acc[w],   mp0 = acc[10+w];
      float nm0 = (shs[1300+w] + mx0*mx0 + mp0*mp0) * 0.25f - 0.5f;
      float r0  = log1pf(fmaxf(nm0, 0.0f));
      float mx1 = acc[w+1], mp1 = acc[11+w];
      float nm1 = (shs[1301+w] + mx1*mx1 + mp1*mp1) * 0.25f - 0.5f;
      float r1  = log1pf(fmaxf(nm1, 0.0f));
      o[w >> 1] = make_float2(r0, r1);
    }
  }
}

extern "C" void kernel_launch(void* const* d_in, const int* in_sizes, int n_in,
                              void* d_out, int out_size, void* d_ws, size_t ws_size,
                              hipStream_t stream)
{
  const float* x    = (const float*)d_in[0];
  const float* i1_0 = (const float*)d_in[1];
  const float* sq_0 = (const float*)d_in[2];
  const float* i2_0 = (const float*)d_in[3];
  const float* dp_0 = (const float*)d_in[4];
  const float* i1_1 = (const float*)d_in[5];
  const float* sq_1 = (const float*)d_in[6];
  const float* i2_1 = (const float*)d_in[7];
  const float* dp_1 = (const float*)d_in[8];
  float* ws = (float*)d_ws;

  int B = in_sizes[0] / 64;

  cvqnn_setup<<<1, 192, 0, stream>>>(i1_0, sq_0, i2_0, dp_0,
                                     i1_1, sq_1, i2_1, dp_1, ws);

  int grid = (B + 255) / 256;   // 256 rows per block, exact, balanced
  cvqnn_main<<<grid, 256, 0, stream>>>(x, ws, (float*)d_out, B);
}